// Round 3
// baseline (513.833 us; speedup 1.0000x reference)
//
#include <hip/hip_runtime.h>
#include <math.h>

#define NB 4
#define NT 4096
#define ND 1024
#define NS 16     // NUM_EXPERTS * NUM_SLOTS
#define NE 8
#define NF 4096

__device__ __forceinline__ float gelu(float v) {
  return 0.5f * v * (1.f + erff(v * 0.70710678118654752f));
}

// ---- zero-fill
__global__ __launch_bounds__(256) void k_zero(float* __restrict__ p, int n) {
  int i = blockIdx.x * 256 + threadIdx.x;
  if (i < n) p[i] = 0.f;
}

// ---- stage A: logits[g][n] = dot(x[g,:], se[n,:]) / 32
// grid NB*NT/4 blocks, 1 token per wave; se read from global (L1/L2-resident 64KB)
__global__ __launch_bounds__(256) void k_logits(const float* __restrict__ x,
                                                const float* __restrict__ se,
                                                float* __restrict__ logits) {
  int wave = threadIdx.x >> 6, lane = threadIdx.x & 63;
  int g = blockIdx.x * 4 + wave;
  float acc[NS];
#pragma unroll
  for (int n = 0; n < NS; ++n) acc[n] = 0.f;
  const float* xr = x + (size_t)g * ND;
  for (int d = lane; d < ND; d += 64) {
    float xv = xr[d];
#pragma unroll
    for (int n = 0; n < NS; ++n) acc[n] += xv * se[n * ND + d];
  }
#pragma unroll
  for (int n = 0; n < NS; ++n) {
#pragma unroll
    for (int off = 32; off > 0; off >>= 1) acc[n] += __shfl_xor(acc[n], off, 64);
  }
  if (lane < NS) logits[(size_t)g * NS + lane] = acc[lane] * 0.03125f;
}

// ---- stage B: per-(b,n) max & sumexp over T. grid NB*NS, block 256
__global__ __launch_bounds__(256) void k_softmax_stats(const float* __restrict__ logits,
                                                       float* __restrict__ stats) {
  int bn = blockIdx.x;
  int b = bn >> 4, n = bn & 15;
  __shared__ float red[256];
  const float* lp = logits + ((size_t)b * NT) * NS + n;
  float m = -1e30f;
  for (int t = threadIdx.x; t < NT; t += 256) m = fmaxf(m, lp[(size_t)t * NS]);
  red[threadIdx.x] = m; __syncthreads();
  for (int s = 128; s > 0; s >>= 1) {
    if (threadIdx.x < s) red[threadIdx.x] = fmaxf(red[threadIdx.x], red[threadIdx.x + s]);
    __syncthreads();
  }
  m = red[0]; __syncthreads();
  float sm = 0.f;
  for (int t = threadIdx.x; t < NT; t += 256) sm += expf(lp[(size_t)t * NS] - m);
  red[threadIdx.x] = sm; __syncthreads();
  for (int s = 128; s > 0; s >>= 1) {
    if (threadIdx.x < s) red[threadIdx.x] += red[threadIdx.x + s];
    __syncthreads();
  }
  if (threadIdx.x == 0) { stats[bn * 2] = m; stats[bn * 2 + 1] = red[0]; }
}

// ---- stage C: slot_in[b][n][d] += dispatch[b][t][n] * x[b][t][d]
// dispatch recomputed inline from logits+stats. grid (tc=16, dc=4, b=NB)
__global__ __launch_bounds__(256) void k_slot_in(const float* __restrict__ x,
                                                 const float* __restrict__ logits,
                                                 const float* __restrict__ stats,
                                                 float* __restrict__ slot_in) {
  __shared__ float s_w[64 * NS];
  __shared__ float s_ms[NS * 2];
  int tc = blockIdx.x, dc = blockIdx.y, b = blockIdx.z;
  if (threadIdx.x < NS * 2) s_ms[threadIdx.x] = stats[b * NS * 2 + threadIdx.x];
  int d = dc * 256 + threadIdx.x;
  float acc[NS];
#pragma unroll
  for (int n = 0; n < NS; ++n) acc[n] = 0.f;
  __syncthreads();
  for (int t0 = tc * 256; t0 < tc * 256 + 256; t0 += 64) {
    __syncthreads();
    for (int i = threadIdx.x; i < 64 * NS; i += 256) {
      int n = i & 15;
      s_w[i] = expf(logits[((size_t)b * NT + t0) * NS + i] - s_ms[n * 2]) / s_ms[n * 2 + 1];
    }
    __syncthreads();
    for (int tt = 0; tt < 64; ++tt) {
      float xv = x[((size_t)b * NT + t0 + tt) * ND + d];
#pragma unroll
      for (int n = 0; n < NS; ++n) acc[n] += s_w[tt * NS + n] * xv;
    }
  }
#pragma unroll
  for (int n = 0; n < NS; ++n)
    atomicAdd(&slot_in[((size_t)b * NS + n) * ND + d], acc[n]);
}

// ---- stage D: LayerNorm over D, IN-PLACE (each thread owns its 4 elems).
__global__ __launch_bounds__(256) void k_layernorm(float* __restrict__ slot_in,
                                                   const float* __restrict__ gamma,
                                                   const float* __restrict__ beta) {
  int row = blockIdx.x;
  __shared__ float red[256];
  float* rp = slot_in + (size_t)row * ND;
  float v[4];
  float sum = 0.f;
#pragma unroll
  for (int j = 0; j < 4; ++j) { v[j] = rp[threadIdx.x + j * 256]; sum += v[j]; }
  red[threadIdx.x] = sum; __syncthreads();
  for (int s = 128; s > 0; s >>= 1) {
    if (threadIdx.x < s) red[threadIdx.x] += red[threadIdx.x + s];
    __syncthreads();
  }
  float mu = red[0] * (1.f / ND); __syncthreads();
  float vs = 0.f;
#pragma unroll
  for (int j = 0; j < 4; ++j) { float t = v[j] - mu; vs += t * t; }
  red[threadIdx.x] = vs; __syncthreads();
  for (int s = 128; s > 0; s >>= 1) {
    if (threadIdx.x < s) red[threadIdx.x] += red[threadIdx.x + s];
    __syncthreads();
  }
  float rstd = rsqrtf(red[0] * (1.f / ND) + 1e-5f);
#pragma unroll
  for (int j = 0; j < 4; ++j) {
    int dd = threadIdx.x + j * 256;
    rp[dd] = (v[j] - mu) * rstd * gamma[dd] + beta[dd];
  }
}

// ---- stage E: u[b,e,s,f] += h[b,e,s,:] @ W1[e,:,f] (split-k over dc, atomics)
// grid (fc=16, dc=2, e=NE); thread <-> f; W1 coalesced over f.
__global__ __launch_bounds__(256) void k_mlp1(const float* __restrict__ h,
                                              const float* __restrict__ W1,
                                              float* __restrict__ u) {
  __shared__ float s_h[8][512];
  int fc = blockIdx.x, dc = blockIdx.y, e = blockIdx.z;
  int f = fc * 256 + threadIdx.x;
  for (int i = threadIdx.x; i < 8 * 512; i += 256) {
    int bs = i >> 9, dd = i & 511;
    int b = bs >> 1, s = bs & 1;
    s_h[bs][dd] = h[((size_t)b * NS + (e * 2 + s)) * ND + dc * 512 + dd];
  }
  __syncthreads();
  float acc[8];
#pragma unroll
  for (int j = 0; j < 8; ++j) acc[j] = 0.f;
  const float* wp = W1 + ((size_t)e * ND + dc * 512) * NF + f;
  for (int dd = 0; dd < 512; ++dd) {
    float w = wp[(size_t)dd * NF];
#pragma unroll
    for (int j = 0; j < 8; ++j) acc[j] += s_h[j][dd] * w;
  }
#pragma unroll
  for (int j = 0; j < 8; ++j) {
    int b = j >> 1, s = j & 1;
    atomicAdd(&u[(((size_t)b * NE + e) * 2 + s) * NF + f], acc[j]);
  }
}

// ---- stage F: slot_out[b,n,d] += gelu(u[b,e,s,:]) @ W2[e,:,d]
// grid (fc=8, dc=4, e=NE); thread <-> d; gelu applied at LDS load.
__global__ __launch_bounds__(256) void k_mlp2(const float* __restrict__ u,
                                              const float* __restrict__ W2,
                                              float* __restrict__ slot_out) {
  __shared__ float s_u[8][512];
  int fc = blockIdx.x, dc = blockIdx.y, e = blockIdx.z;
  int d = dc * 256 + threadIdx.x;
  for (int i = threadIdx.x; i < 8 * 512; i += 256) {
    int bs = i >> 9, ff = i & 511;
    int b = bs >> 1, s = bs & 1;
    s_u[bs][ff] = gelu(u[(((size_t)b * NE + e) * 2 + s) * NF + fc * 512 + ff]);
  }
  __syncthreads();
  float acc[8];
#pragma unroll
  for (int j = 0; j < 8; ++j) acc[j] = 0.f;
  const float* wp = W2 + ((size_t)e * NF + fc * 512) * ND + d;
  for (int ff = 0; ff < 512; ++ff) {
    float w = wp[(size_t)ff * ND];
#pragma unroll
    for (int j = 0; j < 8; ++j) acc[j] += s_u[j][ff] * w;
  }
#pragma unroll
  for (int j = 0; j < 8; ++j) {
    int b = j >> 1, s = j & 1;
    atomicAdd(&slot_out[((size_t)b * NS + (e * 2 + s)) * ND + d], acc[j]);
  }
}

// ---- stage G: combine softmax over 16 slots + weighted sum. grid NB*NT
__global__ __launch_bounds__(256) void k_combine(const float* __restrict__ logits,
                                                 const float* __restrict__ slot_out,
                                                 float* __restrict__ out) {
  int g = blockIdx.x;
  int b = g >> 12;
  __shared__ float s_l[NS];
  if (threadIdx.x < NS) s_l[threadIdx.x] = logits[(size_t)g * NS + threadIdx.x];
  __syncthreads();
  float m = -1e30f;
#pragma unroll
  for (int n = 0; n < NS; ++n) m = fmaxf(m, s_l[n]);
  float c[NS]; float sum = 0.f;
#pragma unroll
  for (int n = 0; n < NS; ++n) { c[n] = expf(s_l[n] - m); sum += c[n]; }
  float rs = 1.f / sum;
#pragma unroll
  for (int j = 0; j < 4; ++j) {
    int d = threadIdx.x + j * 256;
    float o = 0.f;
#pragma unroll
    for (int n = 0; n < NS; ++n) o += c[n] * slot_out[((size_t)b * NS + n) * ND + d];
    out[(size_t)g * ND + d] = o * rs;
  }
}

extern "C" void kernel_launch(void* const* d_in, const int* in_sizes, int n_in,
                              void* d_out, int out_size, void* d_ws, size_t ws_size,
                              hipStream_t stream) {
  const float* x     = (const float*)d_in[0];
  const float* se    = (const float*)d_in[1];
  const float* W1    = (const float*)d_in[2];
  const float* W2    = (const float*)d_in[3];
  const float* gamma = (const float*)d_in[4];
  const float* beta  = (const float*)d_in[5];
  float* out = (float*)d_out;

  // workspace layout (floats), total 655,616 f32 = 2.62 MB
  float* ws       = (float*)d_ws;
  float* logits   = ws;                 // 262144
  float* stats    = ws + 262144;        // 128 (padded to 256)
  float* slot_in  = ws + 262400;        // 65536  (aliased as h after LN)
  float* slot_out = ws + 327936;        // 65536
  float* u        = ws + 393472;        // 262144

  // zero slot_in + slot_out + u (contiguous, 393216 floats)
  k_zero<<<1536, 256, 0, stream>>>(slot_in, 393216);

  k_logits<<<NB * NT / 4, 256, 0, stream>>>(x, se, logits);
  k_softmax_stats<<<NB * NS, 256, 0, stream>>>(logits, stats);
  k_slot_in<<<dim3(16, 4, NB), 256, 0, stream>>>(x, logits, stats, slot_in);
  k_layernorm<<<NB * NS, 256, 0, stream>>>(slot_in, gamma, beta);
  k_mlp1<<<dim3(16, 2, NE), 256, 0, stream>>>(slot_in, W1, u);
  k_mlp2<<<dim3(8, 4, NE), 256, 0, stream>>>(u, W2, slot_out);
  k_combine<<<NB * NT, 256, 0, stream>>>(logits, slot_out, out);
}